// Round 1
// baseline (772.633 us; speedup 1.0000x reference)
//
#include <hip/hip_runtime.h>
#include <stdint.h>

#define B_SZ 4096
#define K_SZ 4
#define D_SZ 1024
#define INV_T 14.285714285714286f   // 1/0.07

typedef __attribute__((ext_vector_type(8))) short bf16x8_t;  // 8 bf16 in 4 VGPRs
typedef __attribute__((ext_vector_type(4))) float f32x4_t;   // MFMA accumulator
typedef unsigned short u16;

// fp32 -> bf16 by truncation (inputs are finite unit-vector components;
// bias ~2^-9 per element -> logit error ~2e-3, threshold is 2.7e-1)
static __device__ __forceinline__ u16 f2bf(float f) {
    union { float f; uint32_t u; } v; v.f = f;
    return (u16)(v.u >> 16);
}

// ---------------------------------------------------------------------------
// Tiled bf16-MFMA "GEMM" that never materializes the product: computes
// exp(dot/T) and reduces into rowsum[] (and optionally colsum[]) atomics.
// X: (M,D) row-major fp32, Y: (N,D) row-major fp32, product Q = X Y^T / T.
// Tile 128x128, 256 threads = 4 waves, each wave a 64x64 quadrant of
// 4x4 x (16x16x32) MFMA tiles.
// ---------------------------------------------------------------------------
template <bool COLSUM>
__global__ __launch_bounds__(256) void gemm_expsum(
    const float* __restrict__ X, const float* __restrict__ Y,
    float* __restrict__ rowsum, float* __restrict__ colsum)
{
    __shared__ u16 As[128][32];   // [row within tile][k within chunk]
    __shared__ u16 Bs[128][32];

    const int m0   = blockIdx.y * 128;
    const int n0   = blockIdx.x * 128;
    const int tid  = threadIdx.x;
    const int lane = tid & 63;
    const int w    = tid >> 6;          // wave 0..3
    const int wm   = (w & 1) * 64;      // wave row offset
    const int wn   = (w >> 1) * 64;     // wave col offset
    const int lr   = lane & 15;
    const int q    = lane >> 4;         // quad 0..3

    f32x4_t acc[4][4];
#pragma unroll
    for (int i = 0; i < 4; i++)
#pragma unroll
        for (int j = 0; j < 4; j++) acc[i][j] = (f32x4_t){0.f, 0.f, 0.f, 0.f};

    // staging decomposition: 256 threads cover 128 rows x 32 k (as float4)
    const int kv = (tid & 7) * 4;   // k offset (float4-granular), 0..28
    const int r0 = tid >> 3;        // row 0..31 (stride 32 over 4 iters)
    const float* xb = X + (size_t)(m0 + r0) * D_SZ + kv;
    const float* yb = Y + (size_t)(n0 + r0) * D_SZ + kv;

    for (int k0 = 0; k0 < D_SZ; k0 += 32) {
#pragma unroll
        for (int i = 0; i < 4; i++) {
            float4 a = *(const float4*)(xb + (size_t)(32 * i) * D_SZ + k0);
            float4 b = *(const float4*)(yb + (size_t)(32 * i) * D_SZ + k0);
            ushort4 ua, ub;
            ua.x = f2bf(a.x); ua.y = f2bf(a.y); ua.z = f2bf(a.z); ua.w = f2bf(a.w);
            ub.x = f2bf(b.x); ub.y = f2bf(b.y); ub.z = f2bf(b.z); ub.w = f2bf(b.w);
            *(ushort4*)&As[r0 + 32 * i][kv] = ua;
            *(ushort4*)&Bs[r0 + 32 * i][kv] = ub;
        }
        __syncthreads();

        // A frag: lane holds A[m=lr][k=8q+j]; B frag: B[n=lr][k=8q+j]
        bf16x8_t af[4], bfr[4];
#pragma unroll
        for (int mt = 0; mt < 4; mt++)
            af[mt] = *(const bf16x8_t*)&As[wm + 16 * mt + lr][8 * q];
#pragma unroll
        for (int nt = 0; nt < 4; nt++)
            bfr[nt] = *(const bf16x8_t*)&Bs[wn + 16 * nt + lr][8 * q];

#pragma unroll
        for (int mt = 0; mt < 4; mt++)
#pragma unroll
            for (int nt = 0; nt < 4; nt++)
                acc[mt][nt] = __builtin_amdgcn_mfma_f32_16x16x32_bf16(
                    af[mt], bfr[nt], acc[mt][nt], 0, 0, 0);
        __syncthreads();
    }

    // Epilogue: e = exp(q). C/D layout: row = 4*q + reg, col = lr (verified m89/m91).
    float rowp[4][4];
#pragma unroll
    for (int mt = 0; mt < 4; mt++)
#pragma unroll
        for (int r = 0; r < 4; r++) rowp[mt][r] = 0.f;

#pragma unroll
    for (int nt = 0; nt < 4; nt++) {
        float colp = 0.f;
#pragma unroll
        for (int mt = 0; mt < 4; mt++) {
#pragma unroll
            for (int r = 0; r < 4; r++) {
                float e = __expf(acc[mt][nt][r] * INV_T);
                colp += e;
                rowp[mt][r] += e;
            }
        }
        if (COLSUM) {
            // lanes L, L^16, L^32, L^48 share a column
            colp += __shfl_xor(colp, 16);
            colp += __shfl_xor(colp, 32);
            if (q == 0)
                atomicAdd(&colsum[n0 + wn + 16 * nt + lr], colp);
        }
    }
#pragma unroll
    for (int mt = 0; mt < 4; mt++) {
#pragma unroll
        for (int r = 0; r < 4; r++) {
            float rp = rowp[mt][r];
            rp += __shfl_xor(rp, 1);
            rp += __shfl_xor(rp, 2);
            rp += __shfl_xor(rp, 4);
            rp += __shfl_xor(rp, 8);
            if (lr == 0)
                atomicAdd(&rowsum[m0 + wm + 16 * mt + 4 * q + r], rp);
        }
    }
}

// ---------------------------------------------------------------------------
// Diagonal terms in full fp32: dsum = sum_i img_i.txt_i / T,
// msum = sum_{b,k} txt_b.other_{b,k} / T. One wave per dot product.
// ---------------------------------------------------------------------------
__global__ __launch_bounds__(256) void diag_kernel(
    const float* __restrict__ img, const float* __restrict__ txt,
    const float* __restrict__ other, float* __restrict__ dm)
{
    const int gw   = blockIdx.x * 4 + (threadIdx.x >> 6);
    const int lane = threadIdx.x & 63;
    const float *pa, *pb;
    float* target;
    if (gw < B_SZ) {
        pa = img + (size_t)gw * D_SZ;
        pb = txt + (size_t)gw * D_SZ;
        target = dm;          // dsum
    } else {
        const int g2 = gw - B_SZ;          // 0..16383, row of other_flat
        pa = other + (size_t)g2 * D_SZ;
        pb = txt + (size_t)(g2 >> 2) * D_SZ;
        target = dm + 1;      // msum
    }
    float s = 0.f;
#pragma unroll
    for (int j = 0; j < 4; j++) {
        float4 a = *(const float4*)(pa + 4 * (lane + 64 * j));
        float4 b = *(const float4*)(pb + 4 * (lane + 64 * j));
        s += a.x * b.x + a.y * b.y + a.z * b.z + a.w * b.w;
    }
#pragma unroll
    for (int d = 1; d < 64; d <<= 1) s += __shfl_xor(s, d);
    if (lane == 0) atomicAdd(target, s * INV_T);
}

// ---------------------------------------------------------------------------
// total = 0.5*(mean log rs1 + mean log cs1) - dsum/B
//       + 0.5*(mean log rs2 - msum/(B*K))
// ---------------------------------------------------------------------------
__global__ __launch_bounds__(256) void finalize_kernel(
    const float* __restrict__ rs1, const float* __restrict__ cs1,
    const float* __restrict__ rs2, const float* __restrict__ dm,
    float* __restrict__ out)
{
    float s1 = 0.f, s2 = 0.f, s3 = 0.f;
    for (int i = threadIdx.x; i < B_SZ; i += 256) {
        s1 += __logf(rs1[i]);
        s2 += __logf(cs1[i]);
        s3 += __logf(rs2[i]);
    }
#pragma unroll
    for (int d = 1; d < 64; d <<= 1) {
        s1 += __shfl_xor(s1, d);
        s2 += __shfl_xor(s2, d);
        s3 += __shfl_xor(s3, d);
    }
    __shared__ float red[3][4];
    const int w = threadIdx.x >> 6, lane = threadIdx.x & 63;
    if (lane == 0) { red[0][w] = s1; red[1][w] = s2; red[2][w] = s3; }
    __syncthreads();
    if (threadIdx.x == 0) {
        float S1 = red[0][0] + red[0][1] + red[0][2] + red[0][3];
        float S2 = red[1][0] + red[1][1] + red[1][2] + red[1][3];
        float S3 = red[2][0] + red[2][1] + red[2][2] + red[2][3];
        const float invB = 1.0f / (float)B_SZ;
        float total = 0.5f * (S1 + S2) * invB - dm[0] * invB
                    + 0.5f * (S3 * invB - dm[1] / ((float)B_SZ * K_SZ));
        out[0] = total;
    }
}

extern "C" void kernel_launch(void* const* d_in, const int* in_sizes, int n_in,
                              void* d_out, int out_size, void* d_ws, size_t ws_size,
                              hipStream_t stream) {
    const float* img   = (const float*)d_in[0];
    const float* txt   = (const float*)d_in[1];
    const float* other = (const float*)d_in[2];
    float* out = (float*)d_out;

    float* ws  = (float*)d_ws;
    float* rs1 = ws;                // [4096] row expsums of Q1
    float* cs1 = ws + B_SZ;         // [4096] col expsums of Q1
    float* rs2 = ws + 2 * B_SZ;     // [4096] row expsums of Q2
    float* dm  = ws + 3 * B_SZ;     // dm[0]=dsum, dm[1]=msum

    hipMemsetAsync(d_ws, 0, (3 * B_SZ + 2) * sizeof(float), stream);

    // Q1 = img (4096) x txt (4096): rows + cols
    hipLaunchKernelGGL((gemm_expsum<true>), dim3(B_SZ / 128, B_SZ / 128), dim3(256),
                       0, stream, img, txt, rs1, cs1);
    // Q2 = txt (4096) x other_flat (16384): rows only
    hipLaunchKernelGGL((gemm_expsum<false>), dim3(B_SZ * K_SZ / 128, B_SZ / 128), dim3(256),
                       0, stream, txt, other, rs2, nullptr);
    // diagonal dot products: 4096 + 16384 waves, 4 waves/block
    hipLaunchKernelGGL(diag_kernel, dim3((B_SZ + B_SZ * K_SZ) / 4), dim3(256),
                       0, stream, img, txt, other, dm);
    hipLaunchKernelGGL(finalize_kernel, dim3(1), dim3(256), 0, stream,
                       rs1, cs1, rs2, dm, out);
}

// Round 2
// 462.947 us; speedup vs baseline: 1.6689x; 1.6689x over previous
//
#include <hip/hip_runtime.h>
#include <stdint.h>

#define B_SZ 4096
#define K_SZ 4
#define D_SZ 1024
#define INV_T 14.285714285714286f   // 1/0.07

typedef __attribute__((ext_vector_type(8))) short bf16x8_t;  // 8 bf16 in 4 VGPRs
typedef __attribute__((ext_vector_type(4))) float f32x4_t;   // MFMA accumulator
typedef unsigned short u16;

// fp32 -> bf16 by truncation
static __device__ __forceinline__ u16 f2bf(float f) {
    union { float f; uint32_t u; } v; v.f = f;
    return (u16)(v.u >> 16);
}

// async global->LDS, 16 bytes per lane. Dest must be wave-uniform base +
// lane*16 (we pass the per-lane address that satisfies this identity).
static __device__ __forceinline__ void gl_lds16(const u16* g, u16* l) {
    __builtin_amdgcn_global_load_lds(
        (const __attribute__((address_space(1))) void*)g,
        (__attribute__((address_space(3))) void*)l, 16, 0, 0);
}

// ===========================================================================
// MAIN PATH (needs ~48.2 MB of d_ws)
// ===========================================================================

// ---------------------------------------------------------------------------
// Pass 1: fp32 -> bf16 conversion of all inputs + diagonal dot products.
// One 256-thread block per 1024-elem row. Rows 0..4095: img (dot with txt_b),
// 4096..8191: txt, 8192..24575: other (dot with txt_{b>>2}).
// Per-block partial written to partials[] -- NO same-address atomics.
// ---------------------------------------------------------------------------
__global__ __launch_bounds__(256) void convert_diag(
    const float* __restrict__ img, const float* __restrict__ txt,
    const float* __restrict__ other,
    u16* __restrict__ img_bf, u16* __restrict__ txt_bf, u16* __restrict__ oth_bf,
    float* __restrict__ partials)
{
    const int row = blockIdx.x;
    const int t   = threadIdx.x;

    const float* src;
    const float* dotsrc = nullptr;
    u16* dst;
    float* part = nullptr;

    if (row < B_SZ) {
        src    = img + (size_t)row * D_SZ;
        dst    = img_bf + (size_t)row * D_SZ;
        dotsrc = txt + (size_t)row * D_SZ;
        part   = partials + row;                       // -> dsum pool
    } else if (row < 2 * B_SZ) {
        const int r = row - B_SZ;
        src = txt + (size_t)r * D_SZ;
        dst = txt_bf + (size_t)r * D_SZ;
    } else {
        const int r = row - 2 * B_SZ;                  // 0..16383
        src    = other + (size_t)r * D_SZ;
        dst    = oth_bf + (size_t)r * D_SZ;
        dotsrc = txt + (size_t)(r >> 2) * D_SZ;
        part   = partials + B_SZ + r;                  // -> msum pool
    }

    float4 a = ((const float4*)src)[t];
    ushort4 ua;
    ua.x = f2bf(a.x); ua.y = f2bf(a.y); ua.z = f2bf(a.z); ua.w = f2bf(a.w);
    ((ushort4*)dst)[t] = ua;

    if (part) {
        float4 b = ((const float4*)dotsrc)[t];
        float s = a.x * b.x + a.y * b.y + a.z * b.z + a.w * b.w;
#pragma unroll
        for (int d = 1; d < 64; d <<= 1) s += __shfl_xor(s, d);
        __shared__ float red[4];
        const int w = t >> 6, lane = t & 63;
        if (lane == 0) red[w] = s;
        __syncthreads();
        if (t == 0)
            part[0] = (red[0] + red[1] + red[2] + red[3]) * INV_T;
    }
}

// ---------------------------------------------------------------------------
// Pass 2: bf16 MFMA GEMM with global_load_lds width-16 staging (m97 shape).
// Q = X Y^T / T, reduce exp(Q) into rowsum (and colsum). Tile 128x128,
// 4 waves, each a 64x64 quadrant of 4x4 16x16x32 MFMAs. LDS unpadded
// [128][32] so the wave-uniform-base + lane*16 dest rule holds.
// ---------------------------------------------------------------------------
template <bool COLSUM>
__global__ __launch_bounds__(256) void gemm_expsum_bf(
    const u16* __restrict__ X, const u16* __restrict__ Y,
    float* __restrict__ rowsum, float* __restrict__ colsum)
{
    __shared__ u16 As[128][32];   // 8 KB
    __shared__ u16 Bs[128][32];   // 8 KB

    const int m0   = blockIdx.y * 128;
    const int n0   = blockIdx.x * 128;
    const int tid  = threadIdx.x;
    const int lane = tid & 63;
    const int w    = tid >> 6;
    const int wm   = (w & 1) * 64;
    const int wn   = (w >> 1) * 64;
    const int lr   = lane & 15;
    const int q    = lane >> 4;

    f32x4_t acc[4][4];
#pragma unroll
    for (int i = 0; i < 4; i++)
#pragma unroll
        for (int j = 0; j < 4; j++) acc[i][j] = (f32x4_t){0.f, 0.f, 0.f, 0.f};

    // staging: thread covers 16 bf16 bytes: row tid>>2 (0..63), seg (tid&3)*8
    const int srow = tid >> 2;
    const int sseg = (tid & 3) * 8;
    const u16* xa = X + (size_t)(m0 + srow) * D_SZ + sseg;
    const u16* xb = X + (size_t)(m0 + 64 + srow) * D_SZ + sseg;
    const u16* ya = Y + (size_t)(n0 + srow) * D_SZ + sseg;
    const u16* yb = Y + (size_t)(n0 + 64 + srow) * D_SZ + sseg;
    u16* lA  = &As[srow][sseg];          // == (u16*)As + tid*8 (lane-contig)
    u16* lA2 = &As[64 + srow][sseg];
    u16* lB  = &Bs[srow][sseg];
    u16* lB2 = &Bs[64 + srow][sseg];

    for (int k0 = 0; k0 < D_SZ; k0 += 32) {
        gl_lds16(xa + k0, lA);
        gl_lds16(xb + k0, lA2);
        gl_lds16(ya + k0, lB);
        gl_lds16(yb + k0, lB2);
        __syncthreads();   // compiler drains vmcnt before s_barrier

        bf16x8_t af[4], bfr[4];
#pragma unroll
        for (int mt = 0; mt < 4; mt++)
            af[mt] = *(const bf16x8_t*)&As[wm + 16 * mt + lr][8 * q];
#pragma unroll
        for (int nt = 0; nt < 4; nt++)
            bfr[nt] = *(const bf16x8_t*)&Bs[wn + 16 * nt + lr][8 * q];

#pragma unroll
        for (int mt = 0; mt < 4; mt++)
#pragma unroll
            for (int nt = 0; nt < 4; nt++)
                acc[mt][nt] = __builtin_amdgcn_mfma_f32_16x16x32_bf16(
                    af[mt], bfr[nt], acc[mt][nt], 0, 0, 0);
        __syncthreads();
    }

    // Epilogue. C/D layout: row = 4*q + reg, col = lr.
    float rowp[4][4];
#pragma unroll
    for (int mt = 0; mt < 4; mt++)
#pragma unroll
        for (int r = 0; r < 4; r++) rowp[mt][r] = 0.f;

#pragma unroll
    for (int nt = 0; nt < 4; nt++) {
        float colp = 0.f;
#pragma unroll
        for (int mt = 0; mt < 4; mt++) {
#pragma unroll
            for (int r = 0; r < 4; r++) {
                float e = __expf(acc[mt][nt][r] * INV_T);
                colp += e;
                rowp[mt][r] += e;
            }
        }
        if (COLSUM) {
            colp += __shfl_xor(colp, 16);
            colp += __shfl_xor(colp, 32);
            if (q == 0)
                atomicAdd(&colsum[n0 + wn + 16 * nt + lr], colp);
        }
    }
#pragma unroll
    for (int mt = 0; mt < 4; mt++) {
#pragma unroll
        for (int r = 0; r < 4; r++) {
            float rp = rowp[mt][r];
            rp += __shfl_xor(rp, 1);
            rp += __shfl_xor(rp, 2);
            rp += __shfl_xor(rp, 4);
            rp += __shfl_xor(rp, 8);
            if (lr == 0)
                atomicAdd(&rowsum[m0 + wm + 16 * mt + 4 * q + r], rp);
        }
    }
}

// ---------------------------------------------------------------------------
// Finalize (main path): sums logs of the 3 expsum vectors + the 20480
// diagonal partials.
// total = 0.5*(mean log rs1 + mean log cs1) - dsum/B
//       + 0.5*(mean log rs2 - msum/(B*K))
// ---------------------------------------------------------------------------
__global__ __launch_bounds__(256) void finalize_part(
    const float* __restrict__ rs1, const float* __restrict__ cs1,
    const float* __restrict__ rs2, const float* __restrict__ partials,
    float* __restrict__ out)
{
    float s1 = 0.f, s2 = 0.f, s3 = 0.f, pd = 0.f, pm = 0.f;
    for (int i = threadIdx.x; i < B_SZ; i += 256) {
        s1 += __logf(rs1[i]);
        s2 += __logf(cs1[i]);
        s3 += __logf(rs2[i]);
        pd += partials[i];
    }
    for (int i = threadIdx.x; i < B_SZ * K_SZ; i += 256)
        pm += partials[B_SZ + i];
#pragma unroll
    for (int d = 1; d < 64; d <<= 1) {
        s1 += __shfl_xor(s1, d); s2 += __shfl_xor(s2, d);
        s3 += __shfl_xor(s3, d); pd += __shfl_xor(pd, d);
        pm += __shfl_xor(pm, d);
    }
    __shared__ float red[5][4];
    const int w = threadIdx.x >> 6, lane = threadIdx.x & 63;
    if (lane == 0) {
        red[0][w] = s1; red[1][w] = s2; red[2][w] = s3;
        red[3][w] = pd; red[4][w] = pm;
    }
    __syncthreads();
    if (threadIdx.x == 0) {
        float S1 = red[0][0] + red[0][1] + red[0][2] + red[0][3];
        float S2 = red[1][0] + red[1][1] + red[1][2] + red[1][3];
        float S3 = red[2][0] + red[2][1] + red[2][2] + red[2][3];
        float DS = red[3][0] + red[3][1] + red[3][2] + red[3][3];
        float MS = red[4][0] + red[4][1] + red[4][2] + red[4][3];
        const float invB = 1.0f / (float)B_SZ;
        out[0] = 0.5f * (S1 + S2) * invB - DS * invB
               + 0.5f * (S3 * invB - MS / ((float)B_SZ * K_SZ));
    }
}

// ===========================================================================
// FALLBACK PATH (round-1 kernels, used only if d_ws is too small) -----------
// ===========================================================================
template <bool COLSUM>
__global__ __launch_bounds__(256) void gemm_expsum(
    const float* __restrict__ X, const float* __restrict__ Y,
    float* __restrict__ rowsum, float* __restrict__ colsum)
{
    __shared__ u16 As[128][32];
    __shared__ u16 Bs[128][32];
    const int m0 = blockIdx.y * 128, n0 = blockIdx.x * 128;
    const int tid = threadIdx.x, lane = tid & 63, w = tid >> 6;
    const int wm = (w & 1) * 64, wn = (w >> 1) * 64;
    const int lr = lane & 15, q = lane >> 4;
    f32x4_t acc[4][4];
#pragma unroll
    for (int i = 0; i < 4; i++)
#pragma unroll
        for (int j = 0; j < 4; j++) acc[i][j] = (f32x4_t){0.f, 0.f, 0.f, 0.f};
    const int kv = (tid & 7) * 4, r0 = tid >> 3;
    const float* xb = X + (size_t)(m0 + r0) * D_SZ + kv;
    const float* yb = Y + (size_t)(n0 + r0) * D_SZ + kv;
    for (int k0 = 0; k0 < D_SZ; k0 += 32) {
#pragma unroll
        for (int i = 0; i < 4; i++) {
            float4 a = *(const float4*)(xb + (size_t)(32 * i) * D_SZ + k0);
            float4 b = *(const float4*)(yb + (size_t)(32 * i) * D_SZ + k0);
            ushort4 ua, ub;
            ua.x = f2bf(a.x); ua.y = f2bf(a.y); ua.z = f2bf(a.z); ua.w = f2bf(a.w);
            ub.x = f2bf(b.x); ub.y = f2bf(b.y); ub.z = f2bf(b.z); ub.w = f2bf(b.w);
            *(ushort4*)&As[r0 + 32 * i][kv] = ua;
            *(ushort4*)&Bs[r0 + 32 * i][kv] = ub;
        }
        __syncthreads();
        bf16x8_t af[4], bfr[4];
#pragma unroll
        for (int mt = 0; mt < 4; mt++)
            af[mt] = *(const bf16x8_t*)&As[wm + 16 * mt + lr][8 * q];
#pragma unroll
        for (int nt = 0; nt < 4; nt++)
            bfr[nt] = *(const bf16x8_t*)&Bs[wn + 16 * nt + lr][8 * q];
#pragma unroll
        for (int mt = 0; mt < 4; mt++)
#pragma unroll
            for (int nt = 0; nt < 4; nt++)
                acc[mt][nt] = __builtin_amdgcn_mfma_f32_16x16x32_bf16(
                    af[mt], bfr[nt], acc[mt][nt], 0, 0, 0);
        __syncthreads();
    }
    float rowp[4][4];
#pragma unroll
    for (int mt = 0; mt < 4; mt++)
#pragma unroll
        for (int r = 0; r < 4; r++) rowp[mt][r] = 0.f;
#pragma unroll
    for (int nt = 0; nt < 4; nt++) {
        float colp = 0.f;
#pragma unroll
        for (int mt = 0; mt < 4; mt++)
#pragma unroll
            for (int r = 0; r < 4; r++) {
                float e = __expf(acc[mt][nt][r] * INV_T);
                colp += e; rowp[mt][r] += e;
            }
        if (COLSUM) {
            colp += __shfl_xor(colp, 16);
            colp += __shfl_xor(colp, 32);
            if (q == 0) atomicAdd(&colsum[n0 + wn + 16 * nt + lr], colp);
        }
    }
#pragma unroll
    for (int mt = 0; mt < 4; mt++)
#pragma unroll
        for (int r = 0; r < 4; r++) {
            float rp = rowp[mt][r];
            rp += __shfl_xor(rp, 1); rp += __shfl_xor(rp, 2);
            rp += __shfl_xor(rp, 4); rp += __shfl_xor(rp, 8);
            if (lr == 0) atomicAdd(&rowsum[m0 + wm + 16 * mt + 4 * q + r], rp);
        }
}

__global__ __launch_bounds__(256) void diag_kernel(
    const float* __restrict__ img, const float* __restrict__ txt,
    const float* __restrict__ other, float* __restrict__ dm)
{
    const int gw = blockIdx.x * 4 + (threadIdx.x >> 6);
    const int lane = threadIdx.x & 63;
    const float *pa, *pb; float* target;
    if (gw < B_SZ) {
        pa = img + (size_t)gw * D_SZ; pb = txt + (size_t)gw * D_SZ; target = dm;
    } else {
        const int g2 = gw - B_SZ;
        pa = other + (size_t)g2 * D_SZ; pb = txt + (size_t)(g2 >> 2) * D_SZ;
        target = dm + 1;
    }
    float s = 0.f;
#pragma unroll
    for (int j = 0; j < 4; j++) {
        float4 a = *(const float4*)(pa + 4 * (lane + 64 * j));
        float4 b = *(const float4*)(pb + 4 * (lane + 64 * j));
        s += a.x * b.x + a.y * b.y + a.z * b.z + a.w * b.w;
    }
#pragma unroll
    for (int d = 1; d < 64; d <<= 1) s += __shfl_xor(s, d);
    if (lane == 0) atomicAdd(target, s * INV_T);
}

__global__ __launch_bounds__(256) void finalize_atomic(
    const float* __restrict__ rs1, const float* __restrict__ cs1,
    const float* __restrict__ rs2, const float* __restrict__ dm,
    float* __restrict__ out)
{
    float s1 = 0.f, s2 = 0.f, s3 = 0.f;
    for (int i = threadIdx.x; i < B_SZ; i += 256) {
        s1 += __logf(rs1[i]); s2 += __logf(cs1[i]); s3 += __logf(rs2[i]);
    }
#pragma unroll
    for (int d = 1; d < 64; d <<= 1) {
        s1 += __shfl_xor(s1, d); s2 += __shfl_xor(s2, d); s3 += __shfl_xor(s3, d);
    }
    __shared__ float red[3][4];
    const int w = threadIdx.x >> 6, lane = threadIdx.x & 63;
    if (lane == 0) { red[0][w] = s1; red[1][w] = s2; red[2][w] = s3; }
    __syncthreads();
    if (threadIdx.x == 0) {
        float S1 = red[0][0] + red[0][1] + red[0][2] + red[0][3];
        float S2 = red[1][0] + red[1][1] + red[1][2] + red[1][3];
        float S3 = red[2][0] + red[2][1] + red[2][2] + red[2][3];
        const float invB = 1.0f / (float)B_SZ;
        out[0] = 0.5f * (S1 + S2) * invB - dm[0] * invB
               + 0.5f * (S3 * invB - dm[1] / ((float)B_SZ * K_SZ));
    }
}

// ===========================================================================
extern "C" void kernel_launch(void* const* d_in, const int* in_sizes, int n_in,
                              void* d_out, int out_size, void* d_ws, size_t ws_size,
                              hipStream_t stream) {
    const float* img   = (const float*)d_in[0];
    const float* txt   = (const float*)d_in[1];
    const float* other = (const float*)d_in[2];
    float* out = (float*)d_out;
    float* ws  = (float*)d_ws;

    // float-region layout
    float* rs1      = ws;                    // [4096]
    float* cs1      = ws + B_SZ;             // [4096]
    float* rs2      = ws + 2 * B_SZ;         // [4096]
    float* partials = ws + 3 * B_SZ;         // [20480]  (main path)
    float* dm       = ws + 3 * B_SZ;         // [2]      (fallback path)

    const size_t hdr_floats = 3 * B_SZ + B_SZ + B_SZ * K_SZ;   // 32768
    const size_t bf_bytes   = (size_t)(2 * B_SZ + B_SZ * K_SZ) * D_SZ * 2; // 48 MB
    const size_t need = hdr_floats * sizeof(float) + bf_bytes;

    if (ws_size >= need) {
        u16* img_bf = (u16*)(ws + hdr_floats);
        u16* txt_bf = img_bf + (size_t)B_SZ * D_SZ;
        u16* oth_bf = txt_bf + (size_t)B_SZ * D_SZ;

        hipMemsetAsync(d_ws, 0, 3 * B_SZ * sizeof(float), stream);
        hipLaunchKernelGGL(convert_diag, dim3(2 * B_SZ + B_SZ * K_SZ), dim3(256),
                           0, stream, img, txt, other, img_bf, txt_bf, oth_bf,
                           partials);
        hipLaunchKernelGGL((gemm_expsum_bf<true>), dim3(B_SZ / 128, B_SZ / 128),
                           dim3(256), 0, stream, img_bf, txt_bf, rs1, cs1);
        hipLaunchKernelGGL((gemm_expsum_bf<false>),
                           dim3(B_SZ * K_SZ / 128, B_SZ / 128), dim3(256), 0,
                           stream, txt_bf, oth_bf, rs2, nullptr);
        hipLaunchKernelGGL(finalize_part, dim3(1), dim3(256), 0, stream,
                           rs1, cs1, rs2, partials, out);
    } else {
        hipMemsetAsync(d_ws, 0, (3 * B_SZ + 2) * sizeof(float), stream);
        hipLaunchKernelGGL((gemm_expsum<true>), dim3(B_SZ / 128, B_SZ / 128),
                           dim3(256), 0, stream, img, txt, rs1, cs1);
        hipLaunchKernelGGL((gemm_expsum<false>),
                           dim3(B_SZ * K_SZ / 128, B_SZ / 128), dim3(256), 0,
                           stream, txt, other, rs2, nullptr);
        hipLaunchKernelGGL(diag_kernel, dim3((B_SZ + B_SZ * K_SZ) / 4),
                           dim3(256), 0, stream, img, txt, other, dm);
        hipLaunchKernelGGL(finalize_atomic, dim3(1), dim3(256), 0, stream,
                           rs1, cs1, rs2, dm, out);
    }
}